// Round 13
// baseline (948.556 us; speedup 1.0000x reference)
//
#include <hip/hip_runtime.h>
#include <math.h>

#define NEG_SLOPE 0.2f

__device__ __forceinline__ float lrelu(float x){ return x > 0.f ? x : NEG_SLOPE * x; }
__device__ __forceinline__ float bf_lo(unsigned u){ return __uint_as_float(u << 16); }
__device__ __forceinline__ float bf_hi(unsigned u){ return __uint_as_float(u & 0xffff0000u); }
__device__ __forceinline__ unsigned short f2bf(float v){
  unsigned ub = __float_as_uint(v);
  return (unsigned short)((ub + 0x7FFFu + ((ub >> 16) & 1u)) >> 16);   // RNE
}

// ---------------- transform v2 (LDS-safe): chunked W staging ----------------
template<int K>
__global__ __launch_bounds__(256) void transform2_kernel(
    const float* __restrict__ A, const float* __restrict__ W,
    const float* __restrict__ att_s, const float* __restrict__ att_d,
    unsigned short* __restrict__ xs, float* __restrict__ a_src,
    float* __restrict__ a_dst, int N){
  constexpr int KC = (K < 32) ? K : 32;
  __shared__ float sW[KC][128];
  __shared__ float sA[32][K];
  const int tid = threadIdx.x;
  const int j4  = (tid & 31) * 4;          // channel base
  const int ng  = tid >> 5;                // node subgroup 0..7
  const int h   = (tid & 31) >> 3;         // head of j4..j4+3

  const float4 as = *reinterpret_cast<const float4*>(att_s + j4);
  const float4 ad = *reinterpret_cast<const float4*>(att_d + j4);

  const int ntiles = (N + 31) >> 5;
  for (int tile = blockIdx.x; tile < ntiles; tile += gridDim.x){
    const int n0 = tile << 5;
    for (int idx = tid; idx < 32 * K; idx += 256){
      int nn = idx / K, kk = idx - nn * K;
      int node = n0 + nn;
      sA[nn][kk] = (node < N) ? A[(size_t)node * K + kk] : 0.f;
    }

    float acc[4][4];
    #pragma unroll
    for (int m = 0; m < 4; ++m)
      #pragma unroll
      for (int e = 0; e < 4; ++e) acc[m][e] = 0.f;

    for (int kc0 = 0; kc0 < K; kc0 += KC){
      __syncthreads();
      for (int idx = tid; idx < KC * 128; idx += 256)
        sW[idx >> 7][idx & 127] = W[(size_t)(kc0 + (idx >> 7)) * 128 + (idx & 127)];
      __syncthreads();
      #pragma unroll 4
      for (int k = 0; k < KC; ++k){
        const float4 w = *reinterpret_cast<const float4*>(&sW[k][j4]);
        #pragma unroll
        for (int m = 0; m < 4; ++m){
          const float a = sA[ng * 4 + m][kc0 + k];
          acc[m][0] += a * w.x; acc[m][1] += a * w.y;
          acc[m][2] += a * w.z; acc[m][3] += a * w.w;
        }
      }
    }

    #pragma unroll
    for (int m = 0; m < 4; ++m){
      const int node = n0 + ng * 4 + m;
      const bool ok = node < N;
      if (ok){
        uint2 pk;
        pk.x = (unsigned)f2bf(acc[m][0]) | ((unsigned)f2bf(acc[m][1]) << 16);
        pk.y = (unsigned)f2bf(acc[m][2]) | ((unsigned)f2bf(acc[m][3]) << 16);
        *reinterpret_cast<uint2*>(xs + (size_t)node * 128 + j4) = pk;
      }
      float ss = acc[m][0]*as.x + acc[m][1]*as.y + acc[m][2]*as.z + acc[m][3]*as.w;
      float sd = acc[m][0]*ad.x + acc[m][1]*ad.y + acc[m][2]*ad.z + acc[m][3]*ad.w;
      #pragma unroll
      for (int d = 1; d < 8; d <<= 1){ ss += __shfl_xor(ss, d); sd += __shfl_xor(sd, d); }
      if (ok && (tid & 7) == 0){
        a_src[node * 4 + h] = ss;
        a_dst[node * 4 + h] = sd;
      }
    }
    __syncthreads();
  }
}

// ---------------- CSR build ----------------
__global__ void count_kernel(const int* __restrict__ ei, int E, int* __restrict__ cnt){
  int e = blockIdx.x * blockDim.x + threadIdx.x;
  if (e < E) atomicAdd(&cnt[ei[E + e]], 1);   // row 1 = dst
}

__global__ void blocksum_kernel(const int* __restrict__ cnt, int N, int* __restrict__ bsum){
  const int base = blockIdx.x * 1024;
  int s = 0;
  for (int i = threadIdx.x; i < 1024; i += 256){
    int idx = base + i;
    if (idx < N) s += cnt[idx];
  }
  #pragma unroll
  for (int d = 1; d < 64; d <<= 1) s += __shfl_xor(s, d);
  __shared__ int ws[4];
  if ((threadIdx.x & 63) == 0) ws[threadIdx.x >> 6] = s;
  __syncthreads();
  if (threadIdx.x == 0) bsum[blockIdx.x] = ws[0] + ws[1] + ws[2] + ws[3];
}

__global__ void bscan_kernel(int* __restrict__ bsum, int nb){   // nb <= 64
  int t = threadIdx.x;
  int v = (t < nb) ? bsum[t] : 0;
  int x = v;
  #pragma unroll
  for (int d = 1; d < 64; d <<= 1){ int y = __shfl_up(x, d); if (t >= d) x += y; }
  if (t < nb) bsum[t] = x - v;            // exclusive
}

__global__ void scanwrite_kernel(const int* __restrict__ cnt, const int* __restrict__ bsum,
                                 int N, int* __restrict__ rp, int* __restrict__ cur){
  const int b = blockIdx.x, t = threadIdx.x;
  const int base = b * 1024 + t * 4;
  int v0=0,v1=0,v2=0,v3=0;
  if (base + 0 < N) v0 = cnt[base + 0];
  if (base + 1 < N) v1 = cnt[base + 1];
  if (base + 2 < N) v2 = cnt[base + 2];
  if (base + 3 < N) v3 = cnt[base + 3];
  const int tsum = v0 + v1 + v2 + v3;
  int x = tsum;
  const int lane = t & 63;
  #pragma unroll
  for (int d = 1; d < 64; d <<= 1){ int y = __shfl_up(x, d); if (lane >= d) x += y; }
  __shared__ int ws[4];
  if (lane == 63) ws[t >> 6] = x;
  __syncthreads();
  int ofs = bsum[b];
  for (int w = 0; w < (t >> 6); ++w) ofs += ws[w];
  int start = ofs + (x - tsum);
  int r1 = start + v0, r2 = r1 + v1, r3 = r2 + v2, r4 = r3 + v3;
  if (base + 0 < N){ rp[base + 1] = r1; cur[base + 0] = start; }
  if (base + 1 < N){ rp[base + 2] = r2; cur[base + 1] = r1; }
  if (base + 2 < N){ rp[base + 3] = r3; cur[base + 2] = r2; }
  if (base + 3 < N){ rp[base + 4] = r4; cur[base + 3] = r3; }
  if (b == 0 && t == 0) rp[0] = 0;
}

__global__ void fill_cov_kernel(const int* __restrict__ ei, int E,
                                int* __restrict__ cur, int* __restrict__ csrc){
  int e = blockIdx.x * blockDim.x + threadIdx.x;
  if (e >= E) return;
  int src = ei[e];
  int dst = ei[E + e];
  int pos = atomicAdd(&cur[dst], 1);
  csrc[pos] = src;
}

// ---- distance fill: two-pass bucketed (reduce dirty-line count) ----
__global__ void bcurinit_kernel(const int* __restrict__ rp, int* __restrict__ bcur,
                                int N, int nbuk){
  int b = blockIdx.x * blockDim.x + threadIdx.x;
  if (b < nbuk) bcur[b] = rp[min(b << 6, N)];
}

// pass A: append records to dst>>6 bucket regions (active frontier = 782 lines).
// record = (src | (dst&63)<<16, ea_bits); src < 65536 since N = 50000.
__global__ void bucket_kernel(const int* __restrict__ ei, const float* __restrict__ eattr,
                              int E, int* __restrict__ bcur, int2* __restrict__ tmp){
  int e = blockIdx.x * blockDim.x + threadIdx.x;
  if (e >= E) return;
  int src = ei[e];
  int dst = ei[E + e];
  float ea = eattr[e];
  int pos = atomicAdd(&bcur[dst >> 6], 1);
  tmp[pos] = make_int2(src | ((dst & 63) << 16), __float_as_int(ea));
}

// pass B: one block per bucket; rank via LDS counters; scatter confined to the
// block's ~16KB CSR window (single CU -> L2-resident -> ~1x amplification).
__global__ void fill_dist2_kernel(const int* __restrict__ rp, int N,
                                  const int2* __restrict__ tmp, int2* __restrict__ pke){
  __shared__ int lcnt[64];
  __shared__ int lrp[64];
  const int b = blockIdx.x;
  const int t = (int)threadIdx.x;           // keep index arithmetic in int
  const int d0 = b << 6;
  if (t < 64){
    lcnt[t] = 0;
    lrp[t] = rp[min(d0 + t, N)];
  }
  __syncthreads();
  const int wb = lrp[0];
  const int we = rp[min(d0 + 64, N)];
  for (int i = wb + t; i < we; i += (int)blockDim.x){
    int2 rec = tmp[i];                        // coalesced read
    int d = (rec.x >> 16) & 63;
    int rank = atomicAdd(&lcnt[d], 1);        // LDS atomic
    pke[lrp[d] + rank] = make_int2(rec.x & 0xffff, rec.y);
  }
}

__global__ void loopea_kernel(const int* __restrict__ rp, const int2* __restrict__ pke,
                              float* __restrict__ lea, int N){
  int n = blockIdx.x * blockDim.x + threadIdx.x;
  if (n >= N) return;
  int b = rp[n], e = rp[n+1];
  float s = 0.f;
  for (int i = b; i < e; ++i) s += __int_as_float(pke[i].y);
  lea[n] = s / fmaxf((float)(e - b), 1.f);
}

__global__ void coef_kernel(const float* __restrict__ We1, const float* __restrict__ ae1,
                            const float* __restrict__ We2, const float* __restrict__ ae2,
                            float* __restrict__ coef){
  int t = threadIdx.x;
  if (t < 4){
    float s = 0.f;
    for (int c = 0; c < 32; ++c) s += We1[t*32 + c] * ae1[t*32 + c];
    coef[t] = s;
  } else if (t < 8){
    int h = t - 4;
    float s = 0.f;
    for (int c = 0; c < 32; ++c) s += We2[h*32 + c] * ae2[h*32 + c];
    coef[4 + h] = s;
  }
}

// ---------------- GAT v3: per-wave two-phase (parallel alpha, lean gather) ----------------
template<bool HASE, bool RELU>
__global__ void gat_kernel(const int* __restrict__ rp, const int* __restrict__ csrc,
                           const int2* __restrict__ pke, const float* __restrict__ loopea,
                           const float* __restrict__ coef,
                           const unsigned short* __restrict__ xs, const float* __restrict__ a_src,
                           const float* __restrict__ a_dst, const float* __restrict__ bias,
                           float* __restrict__ out, int N){
  __shared__ float p_sh[4][64][4];
  __shared__ int   s_sh[4][64];
  const int wv = threadIdx.x >> 6;
  const int lane = threadIdx.x & 63;
  const int n = blockIdx.x * 4 + wv;
  if (n >= N) return;

  const int beg = rp[n], end = rp[n+1];
  const int c = lane * 2;                 // this lane owns channels c, c+1
  const int h = lane >> 4;                // head of those channels

  const float4 adv = *reinterpret_cast<const float4*>(a_dst + (size_t)n*4);
  float4 cf = make_float4(0.f,0.f,0.f,0.f);
  if (HASE) cf = *reinterpret_cast<const float4*>(coef);
  const float adh = (h==0)?adv.x:(h==1)?adv.y:(h==2)?adv.z:adv.w;
  const float chh = (h==0)?cf.x:(h==1)?cf.y:(h==2)?cf.z:cf.w;

  float p;
  {
    float lea = HASE ? loopea[n] : 0.f;
    p = __expf(lrelu(a_src[(size_t)n*4 + h] + adh + lea * chh));
  }
  float denom = p;
  unsigned us = *reinterpret_cast<const unsigned*>(xs + (size_t)n*128 + c);
  float accx = p * bf_lo(us);
  float accy = p * bf_hi(us);

  for (int c0 = beg; c0 < end; c0 += 64){
    const int cnt = min(64, end - c0);
    // ---- phase A ----
    if (lane < cnt){
      int s; float ea = 0.f;
      if (HASE){
        int2 rec = pke[c0 + lane];
        s = rec.x; ea = __int_as_float(rec.y);
      } else {
        s = csrc[c0 + lane];
      }
      const float4 av = *reinterpret_cast<const float4*>(a_src + (size_t)s*4);
      float4 pv;
      pv.x = __expf(lrelu(av.x + adv.x + ea*cf.x));
      pv.y = __expf(lrelu(av.y + adv.y + ea*cf.y));
      pv.z = __expf(lrelu(av.z + adv.z + ea*cf.z));
      pv.w = __expf(lrelu(av.w + adv.w + ea*cf.w));
      *reinterpret_cast<float4*>(&p_sh[wv][lane][0]) = pv;
      s_sh[wv][lane] = s;
    }
    // ---- phase B ----
    #pragma unroll 4
    for (int i = 0; i < cnt; ++i){
      const int s = s_sh[wv][i];
      const float pf = p_sh[wv][i][h];
      denom += pf;
      unsigned u = *reinterpret_cast<const unsigned*>(xs + (size_t)s*128 + c);
      accx += pf * bf_lo(u);
      accy += pf * bf_hi(u);
    }
  }

  const float inv = 1.f / (denom + 1e-16f);
  float ox = accx * inv + bias[c];
  float oy = accy * inv + bias[c+1];
  if (RELU){ ox = fmaxf(ox, 0.f); oy = fmaxf(oy, 0.f); }
  out[(size_t)n*128 + c]     = ox;
  out[(size_t)n*128 + c + 1] = oy;
}

// ---------------- pooling (sorted-batch segment reduction, few atomics) ----------------
template<bool COUNT>
__global__ void pool_kernel(const float* __restrict__ a, const int* __restrict__ batch,
                            float* __restrict__ sums, int* __restrict__ cnts, int N){
  const int j = threadIdx.x;                 // channel 0..127
  const int n0 = blockIdx.x * 32;
  const int n1 = min(n0 + 32, N);
  if (n0 >= N) return;
  int g = batch[n0];
  float acc = 0.f;
  int cnt = 0;
  for (int n = n0; n < n1; ++n){
    int gn = batch[n];
    if (gn != g){
      atomicAdd(&sums[g*128 + j], 0.5f * acc);
      if (COUNT && j == 0) atomicAdd(&cnts[g], cnt);
      acc = 0.f; cnt = 0; g = gn;
    }
    acc += a[(size_t)n*128 + j];
    ++cnt;
  }
  atomicAdd(&sums[g*128 + j], 0.5f * acc);
  if (COUNT && j == 0) atomicAdd(&cnts[g], cnt);
}

__global__ void head_kernel(const float* __restrict__ sums, const int* __restrict__ cnts,
                            const float* __restrict__ ffW, const float* __restrict__ ffb,
                            const float* __restrict__ outW, const float* __restrict__ outb,
                            float* __restrict__ out){
  int g = blockIdx.x, j = threadIdx.x;   // 64 blocks x 128 threads
  __shared__ float mean[128];
  __shared__ float red[128];
  float cnt = fmaxf((float)cnts[g], 1.f);
  mean[j] = sums[g*128 + j] / cnt;
  __syncthreads();
  float acc = ffb[j];
  #pragma unroll 8
  for (int k = 0; k < 128; ++k) acc += mean[k] * ffW[k*128 + j];
  acc = fmaxf(acc, 0.f);
  red[j] = acc * outW[j];
  __syncthreads();
  for (int s = 64; s > 0; s >>= 1){
    if (j < s) red[j] += red[j + s];
    __syncthreads();
  }
  if (j == 0) out[g] = 1.f / (1.f + expf(-(red[0] + outb[0])));
}

// ---------------- host launch ----------------
extern "C" void kernel_launch(void* const* d_in, const int* in_sizes, int n_in,
                              void* d_out, int out_size, void* d_ws, size_t ws_size,
                              hipStream_t stream) {
  const float* x     = (const float*)d_in[0];
  const int*   cov   = (const int*)d_in[1];
  const int*   dist  = (const int*)d_in[2];
  const float* dattr = (const float*)d_in[3];
  const int*   batch = (const int*)d_in[4];
  const float* W_c1 = (const float*)d_in[5],  *as_c1 = (const float*)d_in[6],
             *ad_c1 = (const float*)d_in[7],  *b_c1  = (const float*)d_in[8];
  const float* W_c2 = (const float*)d_in[9],  *as_c2 = (const float*)d_in[10],
             *ad_c2 = (const float*)d_in[11], *b_c2  = (const float*)d_in[12];
  const float* W_d1 = (const float*)d_in[13], *as_d1 = (const float*)d_in[14],
             *ad_d1 = (const float*)d_in[15], *b_d1  = (const float*)d_in[16];
  const float* W_d2 = (const float*)d_in[17], *as_d2 = (const float*)d_in[18],
             *ad_d2 = (const float*)d_in[19], *b_d2  = (const float*)d_in[20];
  const float* We_d1 = (const float*)d_in[21], *ae_d1 = (const float*)d_in[22];
  const float* We_d2 = (const float*)d_in[23], *ae_d2 = (const float*)d_in[24];
  const float* ffW = (const float*)d_in[25], *ffb = (const float*)d_in[26];
  const float* outW = (const float*)d_in[27], *outb = (const float*)d_in[28];
  float* out = (float*)d_out;

  const int N  = in_sizes[0] / 32;
  const int Ec = in_sizes[1] / 2;
  const int Ed = in_sizes[2] / 2;

  char* p = (char*)d_ws;
  auto alloc = [&](size_t bytes) -> void* {
    void* r = (void*)p;
    p += (bytes + 255) & ~(size_t)255;
    return r;
  };
  float*          act    = (float*)alloc((size_t)N * 128 * 4);
  unsigned short* xs     = (unsigned short*)alloc((size_t)N * 128 * 2);
  float*          a_s    = (float*)alloc((size_t)N * 4 * 4);
  float*          a_d    = (float*)alloc((size_t)N * 4 * 4);
  int*            rp_c   = (int*)alloc((size_t)(N + 1) * 4);
  int*            rp_d   = (int*)alloc((size_t)(N + 1) * 4);
  int*            csrc_c = (int*)alloc((size_t)Ec * 4);
  int2*           pke_d  = (int2*)alloc((size_t)Ed * 8);
  int2*           tmp_d  = (int2*)alloc((size_t)Ed * 8);
  int*            cnt    = (int*)alloc((size_t)N * 4);
  int*            cur    = (int*)alloc((size_t)N * 4);
  float*          lea    = (float*)alloc((size_t)N * 4);
  float*          coef   = (float*)alloc(8 * 4);
  float*          sums   = (float*)alloc(64 * 128 * 4);
  int*            cnts   = (int*)alloc(64 * 4);
  int*            bsum   = (int*)alloc(256 * 4);
  int*            bcur   = (int*)alloc(1024 * 4);

  const int TB = 256;
  const int nb   = (N + 1023) / 1024;   // scan chunks
  const int nbuk = (N + 63) / 64;       // dst buckets
  // ---- covalent CSR ----
  hipMemsetAsync(cnt, 0, (size_t)N * 4, stream);
  count_kernel<<<(Ec + TB - 1) / TB, TB, 0, stream>>>(cov, Ec, cnt);
  blocksum_kernel<<<nb, 256, 0, stream>>>(cnt, N, bsum);
  bscan_kernel<<<1, 64, 0, stream>>>(bsum, nb);
  scanwrite_kernel<<<nb, 256, 0, stream>>>(cnt, bsum, N, rp_c, cur);
  fill_cov_kernel<<<(Ec + TB - 1) / TB, TB, 0, stream>>>(cov, Ec, cur, csrc_c);
  // ---- distance CSR (two-pass bucketed) ----
  hipMemsetAsync(cnt, 0, (size_t)N * 4, stream);
  count_kernel<<<(Ed + TB - 1) / TB, TB, 0, stream>>>(dist, Ed, cnt);
  blocksum_kernel<<<nb, 256, 0, stream>>>(cnt, N, bsum);
  bscan_kernel<<<1, 64, 0, stream>>>(bsum, nb);
  scanwrite_kernel<<<nb, 256, 0, stream>>>(cnt, bsum, N, rp_d, cur);
  bcurinit_kernel<<<(nbuk + 255) / 256, 256, 0, stream>>>(rp_d, bcur, N, nbuk);
  bucket_kernel<<<(Ed + TB - 1) / TB, TB, 0, stream>>>(dist, dattr, Ed, bcur, tmp_d);
  fill_dist2_kernel<<<nbuk, 256, 0, stream>>>(rp_d, N, tmp_d, pke_d);
  loopea_kernel<<<(N + TB - 1) / TB, TB, 0, stream>>>(rp_d, pke_d, lea, N);
  coef_kernel<<<1, 64, 0, stream>>>(We_d1, ae_d1, We_d2, ae_d2, coef);

  hipMemsetAsync(sums, 0, 64 * 128 * 4, stream);
  hipMemsetAsync(cnts, 0, 64 * 4, stream);

  const int gatGrid  = (N + 3) / 4;
  const int poolGrid = (N + 31) / 32;
  const int TFB = 1024;
  // ---- covalent branch ----
  transform2_kernel<32><<<TFB, 256, 0, stream>>>(x, W_c1, as_c1, ad_c1, xs, a_s, a_d, N);
  gat_kernel<false, true><<<gatGrid, 256, 0, stream>>>(rp_c, csrc_c, nullptr, nullptr, nullptr,
                                                       xs, a_s, a_d, b_c1, act, N);
  transform2_kernel<128><<<TFB, 256, 0, stream>>>(act, W_c2, as_c2, ad_c2, xs, a_s, a_d, N);
  gat_kernel<false, false><<<gatGrid, 256, 0, stream>>>(rp_c, csrc_c, nullptr, nullptr, nullptr,
                                                        xs, a_s, a_d, b_c2, act, N);
  pool_kernel<true><<<poolGrid, 128, 0, stream>>>(act, batch, sums, cnts, N);
  // ---- distance branch ----
  transform2_kernel<32><<<TFB, 256, 0, stream>>>(x, W_d1, as_d1, ad_d1, xs, a_s, a_d, N);
  gat_kernel<true, true><<<gatGrid, 256, 0, stream>>>(rp_d, nullptr, pke_d, lea, coef,
                                                      xs, a_s, a_d, b_d1, act, N);
  transform2_kernel<128><<<TFB, 256, 0, stream>>>(act, W_d2, as_d2, ad_d2, xs, a_s, a_d, N);
  gat_kernel<true, false><<<gatGrid, 256, 0, stream>>>(rp_d, nullptr, pke_d, lea, coef + 4,
                                                       xs, a_s, a_d, b_d2, act, N);
  pool_kernel<false><<<poolGrid, 128, 0, stream>>>(act, batch, sums, nullptr, N);
  // ---- head ----
  head_kernel<<<64, 128, 0, stream>>>(sums, cnts, ffW, ffb, outW, outb, out);
}

// Round 14
// 759.285 us; speedup vs baseline: 1.2493x; 1.2493x over previous
//
#include <hip/hip_runtime.h>
#include <math.h>

#define NEG_SLOPE 0.2f

__device__ __forceinline__ float lrelu(float x){ return x > 0.f ? x : NEG_SLOPE * x; }
__device__ __forceinline__ float bf_lo(unsigned u){ return __uint_as_float(u << 16); }
__device__ __forceinline__ float bf_hi(unsigned u){ return __uint_as_float(u & 0xffff0000u); }
__device__ __forceinline__ unsigned short f2bf(float v){
  unsigned ub = __float_as_uint(v);
  return (unsigned short)((ub + 0x7FFFu + ((ub >> 16) & 1u)) >> 16);   // RNE
}

// ---------------- transform v2 (LDS-safe): chunked W staging ----------------
template<int K>
__global__ __launch_bounds__(256) void transform2_kernel(
    const float* __restrict__ A, const float* __restrict__ W,
    const float* __restrict__ att_s, const float* __restrict__ att_d,
    unsigned short* __restrict__ xs, float* __restrict__ a_src,
    float* __restrict__ a_dst, int N){
  constexpr int KC = (K < 32) ? K : 32;
  __shared__ float sW[KC][128];
  __shared__ float sA[32][K];
  const int tid = threadIdx.x;
  const int j4  = (tid & 31) * 4;          // channel base
  const int ng  = tid >> 5;                // node subgroup 0..7
  const int h   = (tid & 31) >> 3;         // head of j4..j4+3

  const float4 as = *reinterpret_cast<const float4*>(att_s + j4);
  const float4 ad = *reinterpret_cast<const float4*>(att_d + j4);

  const int ntiles = (N + 31) >> 5;
  for (int tile = blockIdx.x; tile < ntiles; tile += gridDim.x){
    const int n0 = tile << 5;
    for (int idx = tid; idx < 32 * K; idx += 256){
      int nn = idx / K, kk = idx - nn * K;
      int node = n0 + nn;
      sA[nn][kk] = (node < N) ? A[(size_t)node * K + kk] : 0.f;
    }

    float acc[4][4];
    #pragma unroll
    for (int m = 0; m < 4; ++m)
      #pragma unroll
      for (int e = 0; e < 4; ++e) acc[m][e] = 0.f;

    for (int kc0 = 0; kc0 < K; kc0 += KC){
      __syncthreads();
      for (int idx = tid; idx < KC * 128; idx += 256)
        sW[idx >> 7][idx & 127] = W[(size_t)(kc0 + (idx >> 7)) * 128 + (idx & 127)];
      __syncthreads();
      #pragma unroll 4
      for (int k = 0; k < KC; ++k){
        const float4 w = *reinterpret_cast<const float4*>(&sW[k][j4]);
        #pragma unroll
        for (int m = 0; m < 4; ++m){
          const float a = sA[ng * 4 + m][kc0 + k];
          acc[m][0] += a * w.x; acc[m][1] += a * w.y;
          acc[m][2] += a * w.z; acc[m][3] += a * w.w;
        }
      }
    }

    #pragma unroll
    for (int m = 0; m < 4; ++m){
      const int node = n0 + ng * 4 + m;
      const bool ok = node < N;
      if (ok){
        uint2 pk;
        pk.x = (unsigned)f2bf(acc[m][0]) | ((unsigned)f2bf(acc[m][1]) << 16);
        pk.y = (unsigned)f2bf(acc[m][2]) | ((unsigned)f2bf(acc[m][3]) << 16);
        *reinterpret_cast<uint2*>(xs + (size_t)node * 128 + j4) = pk;
      }
      float ss = acc[m][0]*as.x + acc[m][1]*as.y + acc[m][2]*as.z + acc[m][3]*as.w;
      float sd = acc[m][0]*ad.x + acc[m][1]*ad.y + acc[m][2]*ad.z + acc[m][3]*ad.w;
      #pragma unroll
      for (int d = 1; d < 8; d <<= 1){ ss += __shfl_xor(ss, d); sd += __shfl_xor(sd, d); }
      if (ok && (tid & 7) == 0){
        a_src[node * 4 + h] = ss;
        a_dst[node * 4 + h] = sd;
      }
    }
    __syncthreads();
  }
}

// ---------------- CSR build ----------------
__global__ void count_kernel(const int* __restrict__ ei, int E, int* __restrict__ cnt){
  int e = blockIdx.x * blockDim.x + threadIdx.x;
  if (e < E) atomicAdd(&cnt[ei[E + e]], 1);   // row 1 = dst
}

__global__ void blocksum_kernel(const int* __restrict__ cnt, int N, int* __restrict__ bsum){
  const int base = blockIdx.x * 1024;
  int s = 0;
  for (int i = threadIdx.x; i < 1024; i += 256){
    int idx = base + i;
    if (idx < N) s += cnt[idx];
  }
  #pragma unroll
  for (int d = 1; d < 64; d <<= 1) s += __shfl_xor(s, d);
  __shared__ int ws[4];
  if ((threadIdx.x & 63) == 0) ws[threadIdx.x >> 6] = s;
  __syncthreads();
  if (threadIdx.x == 0) bsum[blockIdx.x] = ws[0] + ws[1] + ws[2] + ws[3];
}

__global__ void bscan_kernel(int* __restrict__ bsum, int nb){   // nb <= 64
  int t = threadIdx.x;
  int v = (t < nb) ? bsum[t] : 0;
  int x = v;
  #pragma unroll
  for (int d = 1; d < 64; d <<= 1){ int y = __shfl_up(x, d); if (t >= d) x += y; }
  if (t < nb) bsum[t] = x - v;            // exclusive
}

__global__ void scanwrite_kernel(const int* __restrict__ cnt, const int* __restrict__ bsum,
                                 int N, int* __restrict__ rp, int* __restrict__ cur){
  const int b = blockIdx.x, t = threadIdx.x;
  const int base = b * 1024 + t * 4;
  int v0=0,v1=0,v2=0,v3=0;
  if (base + 0 < N) v0 = cnt[base + 0];
  if (base + 1 < N) v1 = cnt[base + 1];
  if (base + 2 < N) v2 = cnt[base + 2];
  if (base + 3 < N) v3 = cnt[base + 3];
  const int tsum = v0 + v1 + v2 + v3;
  int x = tsum;
  const int lane = t & 63;
  #pragma unroll
  for (int d = 1; d < 64; d <<= 1){ int y = __shfl_up(x, d); if (lane >= d) x += y; }
  __shared__ int ws[4];
  if (lane == 63) ws[t >> 6] = x;
  __syncthreads();
  int ofs = bsum[b];
  for (int w = 0; w < (t >> 6); ++w) ofs += ws[w];
  int start = ofs + (x - tsum);
  int r1 = start + v0, r2 = r1 + v1, r3 = r2 + v2, r4 = r3 + v3;
  if (base + 0 < N){ rp[base + 1] = r1; cur[base + 0] = start; }
  if (base + 1 < N){ rp[base + 2] = r2; cur[base + 1] = r1; }
  if (base + 2 < N){ rp[base + 3] = r3; cur[base + 2] = r2; }
  if (base + 3 < N){ rp[base + 4] = r4; cur[base + 3] = r3; }
  if (b == 0 && t == 0) rp[0] = 0;
}

__global__ void fill_cov_kernel(const int* __restrict__ ei, int E,
                                int* __restrict__ cur, int* __restrict__ csrc){
  int e = blockIdx.x * blockDim.x + threadIdx.x;
  if (e >= E) return;
  int src = ei[e];
  int dst = ei[E + e];
  int pos = atomicAdd(&cur[dst], 1);
  csrc[pos] = src;
}

// distance: scatter packed (src, ea_bits) in ONE 8B store per edge (measured best)
__global__ void fill_dist_kernel(const int* __restrict__ ei, const float* __restrict__ eattr,
                                 int E, int* __restrict__ cur, int2* __restrict__ pke){
  int e = blockIdx.x * blockDim.x + threadIdx.x;
  if (e >= E) return;
  int src = ei[e];
  int dst = ei[E + e];
  float ea = eattr[e];
  int pos = atomicAdd(&cur[dst], 1);
  pke[pos] = make_int2(src, __float_as_int(ea));
}

__global__ void loopea_kernel(const int* __restrict__ rp, const int2* __restrict__ pke,
                              float* __restrict__ lea, int N){
  int n = blockIdx.x * blockDim.x + threadIdx.x;
  if (n >= N) return;
  int b = rp[n], e = rp[n+1];
  float s = 0.f;
  for (int i = b; i < e; ++i) s += __int_as_float(pke[i].y);
  lea[n] = s / fmaxf((float)(e - b), 1.f);
}

__global__ void coef_kernel(const float* __restrict__ We1, const float* __restrict__ ae1,
                            const float* __restrict__ We2, const float* __restrict__ ae2,
                            float* __restrict__ coef){
  int t = threadIdx.x;
  if (t < 4){
    float s = 0.f;
    for (int c = 0; c < 32; ++c) s += We1[t*32 + c] * ae1[t*32 + c];
    coef[t] = s;
  } else if (t < 8){
    int h = t - 4;
    float s = 0.f;
    for (int c = 0; c < 32; ++c) s += We2[h*32 + c] * ae2[h*32 + c];
    coef[4 + h] = s;
  }
}

// ---------------- GAT v4: register-resident src + readlane broadcast ----------------
// Phase A: lane i computes edge i's 4 head-alphas; src stays in a REGISTER.
// Phase B: src via v_readlane (SALU, wave-uniform -> SGPR row base) -- LDS is
// off the gather address path; p (FMA operand only) stays in LDS.
template<bool HASE, bool RELU>
__global__ void gat_kernel(const int* __restrict__ rp, const int* __restrict__ csrc,
                           const int2* __restrict__ pke, const float* __restrict__ loopea,
                           const float* __restrict__ coef,
                           const unsigned short* __restrict__ xs, const float* __restrict__ a_src,
                           const float* __restrict__ a_dst, const float* __restrict__ bias,
                           float* __restrict__ out, int N){
  __shared__ float p_sh[4][64][4];
  const int wv = threadIdx.x >> 6;
  const int lane = threadIdx.x & 63;
  const int n = blockIdx.x * 4 + wv;
  if (n >= N) return;

  const int beg = rp[n], end = rp[n+1];
  const int c = lane * 2;                 // this lane owns channels c, c+1
  const int h = lane >> 4;                // head of those channels

  const float4 adv = *reinterpret_cast<const float4*>(a_dst + (size_t)n*4);
  float4 cf = make_float4(0.f,0.f,0.f,0.f);
  if (HASE) cf = *reinterpret_cast<const float4*>(coef);
  const float adh = (h==0)?adv.x:(h==1)?adv.y:(h==2)?adv.z:adv.w;
  const float chh = (h==0)?cf.x:(h==1)?cf.y:(h==2)?cf.z:cf.w;

  float p;
  {
    float lea = HASE ? loopea[n] : 0.f;
    p = __expf(lrelu(a_src[(size_t)n*4 + h] + adh + lea * chh));
  }
  float denom = p;
  unsigned us = *reinterpret_cast<const unsigned*>(xs + (size_t)n*128 + c);
  float accx = p * bf_lo(us);
  float accy = p * bf_hi(us);

  for (int c0 = beg; c0 < end; c0 += 64){
    const int cnt = min(64, end - c0);
    // ---- phase A: alpha for this lane's edge; src kept in register ----
    int s_reg = 0;
    if (lane < cnt){
      float ea = 0.f;
      if (HASE){
        int2 rec = pke[c0 + lane];
        s_reg = rec.x; ea = __int_as_float(rec.y);
      } else {
        s_reg = csrc[c0 + lane];
      }
      const float4 av = *reinterpret_cast<const float4*>(a_src + (size_t)s_reg*4);
      float4 pv;
      pv.x = __expf(lrelu(av.x + adv.x + ea*cf.x));
      pv.y = __expf(lrelu(av.y + adv.y + ea*cf.y));
      pv.z = __expf(lrelu(av.z + adv.z + ea*cf.z));
      pv.w = __expf(lrelu(av.w + adv.w + ea*cf.w));
      *reinterpret_cast<float4*>(&p_sh[wv][lane][0]) = pv;
    }
    // ---- phase B: readlane src (SGPR base), LDS p off the address path ----
    #pragma unroll 4
    for (int i = 0; i < cnt; ++i){
      const int s = __builtin_amdgcn_readlane(s_reg, i);
      const float pf = p_sh[wv][i][h];
      denom += pf;
      unsigned u = *reinterpret_cast<const unsigned*>(xs + (size_t)s*128 + c);
      accx += pf * bf_lo(u);
      accy += pf * bf_hi(u);
    }
  }

  const float inv = 1.f / (denom + 1e-16f);
  float ox = accx * inv + bias[c];
  float oy = accy * inv + bias[c+1];
  if (RELU){ ox = fmaxf(ox, 0.f); oy = fmaxf(oy, 0.f); }
  out[(size_t)n*128 + c]     = ox;
  out[(size_t)n*128 + c + 1] = oy;
}

// ---------------- pooling (sorted-batch segment reduction, few atomics) ----------------
template<bool COUNT>
__global__ void pool_kernel(const float* __restrict__ a, const int* __restrict__ batch,
                            float* __restrict__ sums, int* __restrict__ cnts, int N){
  const int j = threadIdx.x;                 // channel 0..127
  const int n0 = blockIdx.x * 32;
  const int n1 = min(n0 + 32, N);
  if (n0 >= N) return;
  int g = batch[n0];
  float acc = 0.f;
  int cnt = 0;
  for (int n = n0; n < n1; ++n){
    int gn = batch[n];
    if (gn != g){
      atomicAdd(&sums[g*128 + j], 0.5f * acc);
      if (COUNT && j == 0) atomicAdd(&cnts[g], cnt);
      acc = 0.f; cnt = 0; g = gn;
    }
    acc += a[(size_t)n*128 + j];
    ++cnt;
  }
  atomicAdd(&sums[g*128 + j], 0.5f * acc);
  if (COUNT && j == 0) atomicAdd(&cnts[g], cnt);
}

__global__ void head_kernel(const float* __restrict__ sums, const int* __restrict__ cnts,
                            const float* __restrict__ ffW, const float* __restrict__ ffb,
                            const float* __restrict__ outW, const float* __restrict__ outb,
                            float* __restrict__ out){
  int g = blockIdx.x, j = threadIdx.x;   // 64 blocks x 128 threads
  __shared__ float mean[128];
  __shared__ float red[128];
  float cnt = fmaxf((float)cnts[g], 1.f);
  mean[j] = sums[g*128 + j] / cnt;
  __syncthreads();
  float acc = ffb[j];
  #pragma unroll 8
  for (int k = 0; k < 128; ++k) acc += mean[k] * ffW[k*128 + j];
  acc = fmaxf(acc, 0.f);
  red[j] = acc * outW[j];
  __syncthreads();
  for (int s = 64; s > 0; s >>= 1){
    if (j < s) red[j] += red[j + s];
    __syncthreads();
  }
  if (j == 0) out[g] = 1.f / (1.f + expf(-(red[0] + outb[0])));
}

// ---------------- host launch ----------------
extern "C" void kernel_launch(void* const* d_in, const int* in_sizes, int n_in,
                              void* d_out, int out_size, void* d_ws, size_t ws_size,
                              hipStream_t stream) {
  const float* x     = (const float*)d_in[0];
  const int*   cov   = (const int*)d_in[1];
  const int*   dist  = (const int*)d_in[2];
  const float* dattr = (const float*)d_in[3];
  const int*   batch = (const int*)d_in[4];
  const float* W_c1 = (const float*)d_in[5],  *as_c1 = (const float*)d_in[6],
             *ad_c1 = (const float*)d_in[7],  *b_c1  = (const float*)d_in[8];
  const float* W_c2 = (const float*)d_in[9],  *as_c2 = (const float*)d_in[10],
             *ad_c2 = (const float*)d_in[11], *b_c2  = (const float*)d_in[12];
  const float* W_d1 = (const float*)d_in[13], *as_d1 = (const float*)d_in[14],
             *ad_d1 = (const float*)d_in[15], *b_d1  = (const float*)d_in[16];
  const float* W_d2 = (const float*)d_in[17], *as_d2 = (const float*)d_in[18],
             *ad_d2 = (const float*)d_in[19], *b_d2  = (const float*)d_in[20];
  const float* We_d1 = (const float*)d_in[21], *ae_d1 = (const float*)d_in[22];
  const float* We_d2 = (const float*)d_in[23], *ae_d2 = (const float*)d_in[24];
  const float* ffW = (const float*)d_in[25], *ffb = (const float*)d_in[26];
  const float* outW = (const float*)d_in[27], *outb = (const float*)d_in[28];
  float* out = (float*)d_out;

  const int N  = in_sizes[0] / 32;
  const int Ec = in_sizes[1] / 2;
  const int Ed = in_sizes[2] / 2;

  char* p = (char*)d_ws;
  auto alloc = [&](size_t bytes) -> void* {
    void* r = (void*)p;
    p += (bytes + 255) & ~(size_t)255;
    return r;
  };
  float*          act    = (float*)alloc((size_t)N * 128 * 4);
  unsigned short* xs     = (unsigned short*)alloc((size_t)N * 128 * 2);
  float*          a_s    = (float*)alloc((size_t)N * 4 * 4);
  float*          a_d    = (float*)alloc((size_t)N * 4 * 4);
  int*            rp_c   = (int*)alloc((size_t)(N + 1) * 4);
  int*            rp_d   = (int*)alloc((size_t)(N + 1) * 4);
  int*            csrc_c = (int*)alloc((size_t)Ec * 4);
  int2*           pke_d  = (int2*)alloc((size_t)Ed * 8);
  int*            cnt    = (int*)alloc((size_t)N * 4);
  int*            cur    = (int*)alloc((size_t)N * 4);
  float*          lea    = (float*)alloc((size_t)N * 4);
  float*          coef   = (float*)alloc(8 * 4);
  float*          sums   = (float*)alloc(64 * 128 * 4);
  int*            cnts   = (int*)alloc(64 * 4);
  int*            bsum   = (int*)alloc(256 * 4);

  const int TB = 256;
  const int nb = (N + 1023) / 1024;     // scan chunks
  // ---- covalent CSR ----
  hipMemsetAsync(cnt, 0, (size_t)N * 4, stream);
  count_kernel<<<(Ec + TB - 1) / TB, TB, 0, stream>>>(cov, Ec, cnt);
  blocksum_kernel<<<nb, 256, 0, stream>>>(cnt, N, bsum);
  bscan_kernel<<<1, 64, 0, stream>>>(bsum, nb);
  scanwrite_kernel<<<nb, 256, 0, stream>>>(cnt, bsum, N, rp_c, cur);
  fill_cov_kernel<<<(Ec + TB - 1) / TB, TB, 0, stream>>>(cov, Ec, cur, csrc_c);
  // ---- distance CSR (single-pass, measured best) ----
  hipMemsetAsync(cnt, 0, (size_t)N * 4, stream);
  count_kernel<<<(Ed + TB - 1) / TB, TB, 0, stream>>>(dist, Ed, cnt);
  blocksum_kernel<<<nb, 256, 0, stream>>>(cnt, N, bsum);
  bscan_kernel<<<1, 64, 0, stream>>>(bsum, nb);
  scanwrite_kernel<<<nb, 256, 0, stream>>>(cnt, bsum, N, rp_d, cur);
  fill_dist_kernel<<<(Ed + TB - 1) / TB, TB, 0, stream>>>(dist, dattr, Ed, cur, pke_d);
  loopea_kernel<<<(N + TB - 1) / TB, TB, 0, stream>>>(rp_d, pke_d, lea, N);
  coef_kernel<<<1, 64, 0, stream>>>(We_d1, ae_d1, We_d2, ae_d2, coef);

  hipMemsetAsync(sums, 0, 64 * 128 * 4, stream);
  hipMemsetAsync(cnts, 0, 64 * 4, stream);

  const int gatGrid  = (N + 3) / 4;
  const int poolGrid = (N + 31) / 32;
  const int TFB = 1024;
  // ---- covalent branch ----
  transform2_kernel<32><<<TFB, 256, 0, stream>>>(x, W_c1, as_c1, ad_c1, xs, a_s, a_d, N);
  gat_kernel<false, true><<<gatGrid, 256, 0, stream>>>(rp_c, csrc_c, nullptr, nullptr, nullptr,
                                                       xs, a_s, a_d, b_c1, act, N);
  transform2_kernel<128><<<TFB, 256, 0, stream>>>(act, W_c2, as_c2, ad_c2, xs, a_s, a_d, N);
  gat_kernel<false, false><<<gatGrid, 256, 0, stream>>>(rp_c, csrc_c, nullptr, nullptr, nullptr,
                                                        xs, a_s, a_d, b_c2, act, N);
  pool_kernel<true><<<poolGrid, 128, 0, stream>>>(act, batch, sums, cnts, N);
  // ---- distance branch ----
  transform2_kernel<32><<<TFB, 256, 0, stream>>>(x, W_d1, as_d1, ad_d1, xs, a_s, a_d, N);
  gat_kernel<true, true><<<gatGrid, 256, 0, stream>>>(rp_d, nullptr, pke_d, lea, coef,
                                                      xs, a_s, a_d, b_d1, act, N);
  transform2_kernel<128><<<TFB, 256, 0, stream>>>(act, W_d2, as_d2, ad_d2, xs, a_s, a_d, N);
  gat_kernel<true, false><<<gatGrid, 256, 0, stream>>>(rp_d, nullptr, pke_d, lea, coef + 4,
                                                       xs, a_s, a_d, b_d2, act, N);
  pool_kernel<false><<<poolGrid, 128, 0, stream>>>(act, batch, sums, nullptr, N);
  // ---- head ----
  head_kernel<<<64, 128, 0, stream>>>(sums, cnts, ffW, ffb, outW, outb, out);
}

// Round 16
// 634.671 us; speedup vs baseline: 1.4946x; 1.1963x over previous
//
#include <hip/hip_runtime.h>
#include <math.h>

#define NEG_SLOPE 0.2f

__device__ __forceinline__ float lrelu(float x){ return x > 0.f ? x : NEG_SLOPE * x; }
__device__ __forceinline__ float bf_lo(unsigned u){ return __uint_as_float(u << 16); }
__device__ __forceinline__ float bf_hi(unsigned u){ return __uint_as_float(u & 0xffff0000u); }
__device__ __forceinline__ unsigned short f2bf(float v){
  unsigned ub = __float_as_uint(v);
  return (unsigned short)((ub + 0x7FFFu + ((ub >> 16) & 1u)) >> 16);   // RNE
}

// ---------------- transform v2 (LDS-safe): chunked W staging ----------------
template<int K>
__global__ __launch_bounds__(256) void transform2_kernel(
    const float* __restrict__ A, const float* __restrict__ W,
    const float* __restrict__ att_s, const float* __restrict__ att_d,
    unsigned short* __restrict__ xs, float* __restrict__ a_src,
    float* __restrict__ a_dst, int N){
  constexpr int KC = (K < 32) ? K : 32;
  __shared__ float sW[KC][128];
  __shared__ float sA[32][K];
  const int tid = threadIdx.x;
  const int j4  = (tid & 31) * 4;          // channel base
  const int ng  = tid >> 5;                // node subgroup 0..7
  const int h   = (tid & 31) >> 3;         // head of j4..j4+3

  const float4 as = *reinterpret_cast<const float4*>(att_s + j4);
  const float4 ad = *reinterpret_cast<const float4*>(att_d + j4);

  const int ntiles = (N + 31) >> 5;
  for (int tile = blockIdx.x; tile < ntiles; tile += gridDim.x){
    const int n0 = tile << 5;
    for (int idx = tid; idx < 32 * K; idx += 256){
      int nn = idx / K, kk = idx - nn * K;
      int node = n0 + nn;
      sA[nn][kk] = (node < N) ? A[(size_t)node * K + kk] : 0.f;
    }

    float acc[4][4];
    #pragma unroll
    for (int m = 0; m < 4; ++m)
      #pragma unroll
      for (int e = 0; e < 4; ++e) acc[m][e] = 0.f;

    for (int kc0 = 0; kc0 < K; kc0 += KC){
      __syncthreads();
      for (int idx = tid; idx < KC * 128; idx += 256)
        sW[idx >> 7][idx & 127] = W[(size_t)(kc0 + (idx >> 7)) * 128 + (idx & 127)];
      __syncthreads();
      #pragma unroll 4
      for (int k = 0; k < KC; ++k){
        const float4 w = *reinterpret_cast<const float4*>(&sW[k][j4]);
        #pragma unroll
        for (int m = 0; m < 4; ++m){
          const float a = sA[ng * 4 + m][kc0 + k];
          acc[m][0] += a * w.x; acc[m][1] += a * w.y;
          acc[m][2] += a * w.z; acc[m][3] += a * w.w;
        }
      }
    }

    #pragma unroll
    for (int m = 0; m < 4; ++m){
      const int node = n0 + ng * 4 + m;
      const bool ok = node < N;
      if (ok){
        uint2 pk;
        pk.x = (unsigned)f2bf(acc[m][0]) | ((unsigned)f2bf(acc[m][1]) << 16);
        pk.y = (unsigned)f2bf(acc[m][2]) | ((unsigned)f2bf(acc[m][3]) << 16);
        *reinterpret_cast<uint2*>(xs + (size_t)node * 128 + j4) = pk;
      }
      float ss = acc[m][0]*as.x + acc[m][1]*as.y + acc[m][2]*as.z + acc[m][3]*as.w;
      float sd = acc[m][0]*ad.x + acc[m][1]*ad.y + acc[m][2]*ad.z + acc[m][3]*ad.w;
      #pragma unroll
      for (int d = 1; d < 8; d <<= 1){ ss += __shfl_xor(ss, d); sd += __shfl_xor(sd, d); }
      if (ok && (tid & 7) == 0){
        a_src[node * 4 + h] = ss;
        a_dst[node * 4 + h] = sd;
      }
    }
    __syncthreads();
  }
}

// ---------------- CSR build ----------------
__global__ void count_kernel(const int* __restrict__ ei, int E, int* __restrict__ cnt){
  int e = blockIdx.x * blockDim.x + threadIdx.x;
  if (e < E) atomicAdd(&cnt[ei[E + e]], 1);   // row 1 = dst
}

__global__ void blocksum_kernel(const int* __restrict__ cnt, int N, int* __restrict__ bsum){
  const int base = blockIdx.x * 1024;
  int s = 0;
  for (int i = threadIdx.x; i < 1024; i += 256){
    int idx = base + i;
    if (idx < N) s += cnt[idx];
  }
  #pragma unroll
  for (int d = 1; d < 64; d <<= 1) s += __shfl_xor(s, d);
  __shared__ int ws[4];
  if ((threadIdx.x & 63) == 0) ws[threadIdx.x >> 6] = s;
  __syncthreads();
  if (threadIdx.x == 0) bsum[blockIdx.x] = ws[0] + ws[1] + ws[2] + ws[3];
}

__global__ void bscan_kernel(int* __restrict__ bsum, int nb){   // nb <= 64
  int t = threadIdx.x;
  int v = (t < nb) ? bsum[t] : 0;
  int x = v;
  #pragma unroll
  for (int d = 1; d < 64; d <<= 1){ int y = __shfl_up(x, d); if (t >= d) x += y; }
  if (t < nb) bsum[t] = x - v;            // exclusive
}

__global__ void scanwrite_kernel(const int* __restrict__ cnt, const int* __restrict__ bsum,
                                 int N, int* __restrict__ rp, int* __restrict__ cur){
  const int b = blockIdx.x, t = threadIdx.x;
  const int base = b * 1024 + t * 4;
  int v0=0,v1=0,v2=0,v3=0;
  if (base + 0 < N) v0 = cnt[base + 0];
  if (base + 1 < N) v1 = cnt[base + 1];
  if (base + 2 < N) v2 = cnt[base + 2];
  if (base + 3 < N) v3 = cnt[base + 3];
  const int tsum = v0 + v1 + v2 + v3;
  int x = tsum;
  const int lane = t & 63;
  #pragma unroll
  for (int d = 1; d < 64; d <<= 1){ int y = __shfl_up(x, d); if (lane >= d) x += y; }
  __shared__ int ws[4];
  if (lane == 63) ws[t >> 6] = x;
  __syncthreads();
  int ofs = bsum[b];
  for (int w = 0; w < (t >> 6); ++w) ofs += ws[w];
  int start = ofs + (x - tsum);
  int r1 = start + v0, r2 = r1 + v1, r3 = r2 + v2, r4 = r3 + v3;
  if (base + 0 < N){ rp[base + 1] = r1; cur[base + 0] = start; }
  if (base + 1 < N){ rp[base + 2] = r2; cur[base + 1] = r1; }
  if (base + 2 < N){ rp[base + 3] = r3; cur[base + 2] = r2; }
  if (base + 3 < N){ rp[base + 4] = r4; cur[base + 3] = r3; }
  if (b == 0 && t == 0) rp[0] = 0;
}

__global__ void fill_cov_kernel(const int* __restrict__ ei, int E,
                                int* __restrict__ cur, int* __restrict__ csrc){
  int e = blockIdx.x * blockDim.x + threadIdx.x;
  if (e >= E) return;
  int src = ei[e];
  int dst = ei[E + e];
  int pos = atomicAdd(&cur[dst], 1);
  csrc[pos] = src;
}

// distance fill, XCD-sliced: blocks with (blockIdx&7)==s handle only dst-slice s.
// Slice s's pke window (~1.6MB) stays hot in one XCD's L2 -> lines evicted ~once
// instead of ~8x (cross-XCD bounce). Edge list re-scanned 8x from L3 (cheap).
__global__ void fill_dist_kernel(const int* __restrict__ ei, const float* __restrict__ eattr,
                                 int E, int N, int* __restrict__ cur, int2* __restrict__ pke){
  const int slice  = blockIdx.x & 7;
  const int chunk  = blockIdx.x >> 3;
  const int nchunk = gridDim.x >> 3;
  const int sw = (N + 7) >> 3;
  const int lo = slice * sw;
  const int hi = min(lo + sw, N);
  for (int e = chunk * blockDim.x + threadIdx.x; e < E; e += nchunk * blockDim.x){
    int dst = ei[E + e];
    if (dst >= lo && dst < hi){
      int src = ei[e];
      float ea = eattr[e];
      int pos = atomicAdd(&cur[dst], 1);
      pke[pos] = make_int2(src, __float_as_int(ea));
    }
  }
}

__global__ void loopea_kernel(const int* __restrict__ rp, const int2* __restrict__ pke,
                              float* __restrict__ lea, int N){
  int n = blockIdx.x * blockDim.x + threadIdx.x;
  if (n >= N) return;
  int b = rp[n], e = rp[n+1];
  float s = 0.f;
  for (int i = b; i < e; ++i) s += __int_as_float(pke[i].y);
  lea[n] = s / fmaxf((float)(e - b), 1.f);
}

__global__ void coef_kernel(const float* __restrict__ We1, const float* __restrict__ ae1,
                            const float* __restrict__ We2, const float* __restrict__ ae2,
                            float* __restrict__ coef){
  int t = threadIdx.x;
  if (t < 4){
    float s = 0.f;
    for (int c = 0; c < 32; ++c) s += We1[t*32 + c] * ae1[t*32 + c];
    coef[t] = s;
  } else if (t < 8){
    int h = t - 4;
    float s = 0.f;
    for (int c = 0; c < 32; ++c) s += We2[h*32 + c] * ae2[h*32 + c];
    coef[4 + h] = s;
  }
}

// ---------------- GAT v3 (measured best): per-wave two-phase via LDS ----------------
template<bool HASE, bool RELU>
__global__ void gat_kernel(const int* __restrict__ rp, const int* __restrict__ csrc,
                           const int2* __restrict__ pke, const float* __restrict__ loopea,
                           const float* __restrict__ coef,
                           const unsigned short* __restrict__ xs, const float* __restrict__ a_src,
                           const float* __restrict__ a_dst, const float* __restrict__ bias,
                           float* __restrict__ out, int N){
  __shared__ float p_sh[4][64][4];
  __shared__ int   s_sh[4][64];
  const int wv = threadIdx.x >> 6;
  const int lane = threadIdx.x & 63;
  const int n = blockIdx.x * 4 + wv;
  if (n >= N) return;

  const int beg = rp[n], end = rp[n+1];
  const int c = lane * 2;                 // this lane owns channels c, c+1
  const int h = lane >> 4;                // head of those channels

  const float4 adv = *reinterpret_cast<const float4*>(a_dst + (size_t)n*4);
  float4 cf = make_float4(0.f,0.f,0.f,0.f);
  if (HASE) cf = *reinterpret_cast<const float4*>(coef);
  const float adh = (h==0)?adv.x:(h==1)?adv.y:(h==2)?adv.z:adv.w;
  const float chh = (h==0)?cf.x:(h==1)?cf.y:(h==2)?cf.z:cf.w;

  float p;
  {
    float lea = HASE ? loopea[n] : 0.f;
    p = __expf(lrelu(a_src[(size_t)n*4 + h] + adh + lea * chh));
  }
  float denom = p;
  unsigned us = *reinterpret_cast<const unsigned*>(xs + (size_t)n*128 + c);
  float accx = p * bf_lo(us);
  float accy = p * bf_hi(us);

  for (int c0 = beg; c0 < end; c0 += 64){
    const int cnt = min(64, end - c0);
    // ---- phase A ----
    if (lane < cnt){
      int s; float ea = 0.f;
      if (HASE){
        int2 rec = pke[c0 + lane];
        s = rec.x; ea = __int_as_float(rec.y);
      } else {
        s = csrc[c0 + lane];
      }
      const float4 av = *reinterpret_cast<const float4*>(a_src + (size_t)s*4);
      float4 pv;
      pv.x = __expf(lrelu(av.x + adv.x + ea*cf.x));
      pv.y = __expf(lrelu(av.y + adv.y + ea*cf.y));
      pv.z = __expf(lrelu(av.z + adv.z + ea*cf.z));
      pv.w = __expf(lrelu(av.w + adv.w + ea*cf.w));
      *reinterpret_cast<float4*>(&p_sh[wv][lane][0]) = pv;
      s_sh[wv][lane] = s;
    }
    // ---- phase B ----
    #pragma unroll 4
    for (int i = 0; i < cnt; ++i){
      const int s = s_sh[wv][i];
      const float pf = p_sh[wv][i][h];
      denom += pf;
      unsigned u = *reinterpret_cast<const unsigned*>(xs + (size_t)s*128 + c);
      accx += pf * bf_lo(u);
      accy += pf * bf_hi(u);
    }
  }

  const float inv = 1.f / (denom + 1e-16f);
  float ox = accx * inv + bias[c];
  float oy = accy * inv + bias[c+1];
  if (RELU){ ox = fmaxf(ox, 0.f); oy = fmaxf(oy, 0.f); }
  out[(size_t)n*128 + c]     = ox;
  out[(size_t)n*128 + c + 1] = oy;
}

// ---------------- pooling (sorted-batch segment reduction, few atomics) ----------------
template<bool COUNT>
__global__ void pool_kernel(const float* __restrict__ a, const int* __restrict__ batch,
                            float* __restrict__ sums, int* __restrict__ cnts, int N){
  const int j = threadIdx.x;                 // channel 0..127
  const int n0 = blockIdx.x * 32;
  const int n1 = min(n0 + 32, N);
  if (n0 >= N) return;
  int g = batch[n0];
  float acc = 0.f;
  int cnt = 0;
  for (int n = n0; n < n1; ++n){
    int gn = batch[n];
    if (gn != g){
      atomicAdd(&sums[g*128 + j], 0.5f * acc);
      if (COUNT && j == 0) atomicAdd(&cnts[g], cnt);
      acc = 0.f; cnt = 0; g = gn;
    }
    acc += a[(size_t)n*128 + j];
    ++cnt;
  }
  atomicAdd(&sums[g*128 + j], 0.5f * acc);
  if (COUNT && j == 0) atomicAdd(&cnts[g], cnt);
}

__global__ void head_kernel(const float* __restrict__ sums, const int* __restrict__ cnts,
                            const float* __restrict__ ffW, const float* __restrict__ ffb,
                            const float* __restrict__ outW, const float* __restrict__ outb,
                            float* __restrict__ out){
  int g = blockIdx.x, j = threadIdx.x;   // 64 blocks x 128 threads
  __shared__ float mean[128];
  __shared__ float red[128];
  float cnt = fmaxf((float)cnts[g], 1.f);
  mean[j] = sums[g*128 + j] / cnt;
  __syncthreads();
  float acc = ffb[j];
  #pragma unroll 8
  for (int k = 0; k < 128; ++k) acc += mean[k] * ffW[k*128 + j];
  acc = fmaxf(acc, 0.f);
  red[j] = acc * outW[j];
  __syncthreads();
  for (int s = 64; s > 0; s >>= 1){
    if (j < s) red[j] += red[j + s];
    __syncthreads();
  }
  if (j == 0) out[g] = 1.f / (1.f + expf(-(red[0] + outb[0])));
}

// ---------------- host launch ----------------
extern "C" void kernel_launch(void* const* d_in, const int* in_sizes, int n_in,
                              void* d_out, int out_size, void* d_ws, size_t ws_size,
                              hipStream_t stream) {
  const float* x     = (const float*)d_in[0];
  const int*   cov   = (const int*)d_in[1];
  const int*   dist  = (const int*)d_in[2];
  const float* dattr = (const float*)d_in[3];
  const int*   batch = (const int*)d_in[4];
  const float* W_c1 = (const float*)d_in[5],  *as_c1 = (const float*)d_in[6],
             *ad_c1 = (const float*)d_in[7],  *b_c1  = (const float*)d_in[8];
  const float* W_c2 = (const float*)d_in[9],  *as_c2 = (const float*)d_in[10],
             *ad_c2 = (const float*)d_in[11], *b_c2  = (const float*)d_in[12];
  const float* W_d1 = (const float*)d_in[13], *as_d1 = (const float*)d_in[14],
             *ad_d1 = (const float*)d_in[15], *b_d1  = (const float*)d_in[16];
  const float* W_d2 = (const float*)d_in[17], *as_d2 = (const float*)d_in[18],
             *ad_d2 = (const float*)d_in[19], *b_d2  = (const float*)d_in[20];
  const float* We_d1 = (const float*)d_in[21], *ae_d1 = (const float*)d_in[22];
  const float* We_d2 = (const float*)d_in[23], *ae_d2 = (const float*)d_in[24];
  const float* ffW = (const float*)d_in[25], *ffb = (const float*)d_in[26];
  const float* outW = (const float*)d_in[27], *outb = (const float*)d_in[28];
  float* out = (float*)d_out;

  const int N  = in_sizes[0] / 32;
  const int Ec = in_sizes[1] / 2;
  const int Ed = in_sizes[2] / 2;

  char* p = (char*)d_ws;
  auto alloc = [&](size_t bytes) -> void* {
    void* r = (void*)p;
    p += (bytes + 255) & ~(size_t)255;
    return r;
  };
  float*          act    = (float*)alloc((size_t)N * 128 * 4);
  unsigned short* xs     = (unsigned short*)alloc((size_t)N * 128 * 2);
  float*          a_s    = (float*)alloc((size_t)N * 4 * 4);
  float*          a_d    = (float*)alloc((size_t)N * 4 * 4);
  int*            rp_c   = (int*)alloc((size_t)(N + 1) * 4);
  int*            rp_d   = (int*)alloc((size_t)(N + 1) * 4);
  int*            csrc_c = (int*)alloc((size_t)Ec * 4);
  int2*           pke_d  = (int2*)alloc((size_t)Ed * 8);
  int*            cnt    = (int*)alloc((size_t)N * 4);
  int*            cur    = (int*)alloc((size_t)N * 4);
  float*          lea    = (float*)alloc((size_t)N * 4);
  float*          coef   = (float*)alloc(8 * 4);
  float*          sums   = (float*)alloc(64 * 128 * 4);
  int*            cnts   = (int*)alloc(64 * 4);
  int*            bsum   = (int*)alloc(256 * 4);

  const int TB = 256;
  const int nb = (N + 1023) / 1024;     // scan chunks
  // ---- covalent CSR ----
  hipMemsetAsync(cnt, 0, (size_t)N * 4, stream);
  count_kernel<<<(Ec + TB - 1) / TB, TB, 0, stream>>>(cov, Ec, cnt);
  blocksum_kernel<<<nb, 256, 0, stream>>>(cnt, N, bsum);
  bscan_kernel<<<1, 64, 0, stream>>>(bsum, nb);
  scanwrite_kernel<<<nb, 256, 0, stream>>>(cnt, bsum, N, rp_c, cur);
  fill_cov_kernel<<<(Ec + TB - 1) / TB, TB, 0, stream>>>(cov, Ec, cur, csrc_c);
  // ---- distance CSR (single-pass scatter, XCD-sliced) ----
  hipMemsetAsync(cnt, 0, (size_t)N * 4, stream);
  count_kernel<<<(Ed + TB - 1) / TB, TB, 0, stream>>>(dist, Ed, cnt);
  blocksum_kernel<<<nb, 256, 0, stream>>>(cnt, N, bsum);
  bscan_kernel<<<1, 64, 0, stream>>>(bsum, nb);
  scanwrite_kernel<<<nb, 256, 0, stream>>>(cnt, bsum, N, rp_d, cur);
  fill_dist_kernel<<<2048, TB, 0, stream>>>(dist, dattr, Ed, N, cur, pke_d);
  loopea_kernel<<<(N + TB - 1) / TB, TB, 0, stream>>>(rp_d, pke_d, lea, N);
  coef_kernel<<<1, 64, 0, stream>>>(We_d1, ae_d1, We_d2, ae_d2, coef);

  hipMemsetAsync(sums, 0, 64 * 128 * 4, stream);
  hipMemsetAsync(cnts, 0, 64 * 4, stream);

  const int gatGrid  = (N + 3) / 4;
  const int poolGrid = (N + 31) / 32;
  const int TFB = 1024;
  // ---- covalent branch ----
  transform2_kernel<32><<<TFB, 256, 0, stream>>>(x, W_c1, as_c1, ad_c1, xs, a_s, a_d, N);
  gat_kernel<false, true><<<gatGrid, 256, 0, stream>>>(rp_c, csrc_c, nullptr, nullptr, nullptr,
                                                       xs, a_s, a_d, b_c1, act, N);
  transform2_kernel<128><<<TFB, 256, 0, stream>>>(act, W_c2, as_c2, ad_c2, xs, a_s, a_d, N);
  gat_kernel<false, false><<<gatGrid, 256, 0, stream>>>(rp_c, csrc_c, nullptr, nullptr, nullptr,
                                                        xs, a_s, a_d, b_c2, act, N);
  pool_kernel<true><<<poolGrid, 128, 0, stream>>>(act, batch, sums, cnts, N);
  // ---- distance branch ----
  transform2_kernel<32><<<TFB, 256, 0, stream>>>(x, W_d1, as_d1, ad_d1, xs, a_s, a_d, N);
  gat_kernel<true, true><<<gatGrid, 256, 0, stream>>>(rp_d, nullptr, pke_d, lea, coef,
                                                      xs, a_s, a_d, b_d1, act, N);
  transform2_kernel<128><<<TFB, 256, 0, stream>>>(act, W_d2, as_d2, ad_d2, xs, a_s, a_d, N);
  gat_kernel<true, false><<<gatGrid, 256, 0, stream>>>(rp_d, nullptr, pke_d, lea, coef + 4,
                                                       xs, a_s, a_d, b_d2, act, N);
  pool_kernel<false><<<poolGrid, 128, 0, stream>>>(act, batch, sums, nullptr, N);
  // ---- head ----
  head_kernel<<<64, 128, 0, stream>>>(sums, cnts, ffW, ffb, outW, outb, out);
}